// Round 11
// baseline (229.826 us; speedup 1.0000x reference)
//
#include <hip/hip_runtime.h>
#include <hip/hip_fp16.h>

#define N_NODES 50000
#define N_EDGES 800000
#define D_IN    128
#define D_SH    16
#define D_OUT   128
#define N_PATHS 64

#define SEGN    128                      // nodes per segment (seg = dst>>7)
#define NSEG    391                      // ceil(50000/128)
#define NSEGP   512                      // padded for the 64-lane scan
#define CAPE    2560                     // entries/seg cap (mean 2048, sd 45)

#define EPB     1000                     // edges per scatter block (R18: 2000->1000)
#define BINB    800                      // scatter blocks (800*1000 = 800000)
#define BLKA    512                      // scatter block threads (8 waves)
#define XCB     1563                     // xc blocks (32 nodes each, guarded)
#define BLK2    512                      // node kernel threads (8 waves)

#define QN      32                       // nodes per unit (quarter-segment)
#define QCAP    1024                     // CSR cap (mean 512, sd 23)
#define NUNITS  (NSEG * 4)               // 1564 units
#define NNB     782                      // node blocks; 2 units each (782*2=1564)

// ---------------------------------------------------------------------------
// R18: generation packing + single-pass node scan; scatter TLP x2.
// R17 post-mortem: node occupancy 53% == grid fragmentation (1564 blocks /
// 1024-block residency cap = 1.53 generations; 2nd gen runs 53% full).
// And total-minus-node shows bin_scatter ~50-60us — same disease (400
// blocks = 1.56/CU, latency-exposed). Fixes:
//  * node: 782 blocks x 2 STATIC units (bid, bid+782) -> all blocks
//    co-resident (3.05/CU < 4 cap), identical per-block work, no ragged
//    generation. Single-pass scan: meta staged to LDS while counting;
//    CSR scatter reads LDS (R13's FETCH win, without its persistent-queue
//    structure). LDS 18.9KB -> still wave-capped, not LDS-capped.
//  * scatter: 800 blocks x 1000 edges (3.1/CU, ~25 waves/CU hide pass
//    latency). Short runs raise write amp — R15 proved non-binding.
//  * bin_xc unchanged.
//
// Workspace:
//   segcnt @ 0          : 391*4 (memset 2048 covers)
//   meta   @ 2048       : 391*2560*4  =  4,003,840  (src | dl<<16)
//   sh16   @ 4,005,888  : 391*2560*32 = 32,030,720  (fp16 sh rows)
//   xc_h   @ 36,036,608 : 50000*64*2  =  6,400,000  (fp16 path-major table)
//   total 42,436,608  (< 57.8 MB harness workspace)
// ---------------------------------------------------------------------------
#define OFF_META 2048
#define OFF_SH16 (OFF_META + NSEG*CAPE*4)
#define OFF_XCH  (OFF_SH16 + NSEG*CAPE*32)

__global__ __launch_bounds__(BLKA) void bin_scatter(
        const float* __restrict__ sh, const int* __restrict__ src,
        const int* __restrict__ dst, int* __restrict__ segcnt,
        int* __restrict__ meta, __half* __restrict__ sh16) {
    __shared__ int lcnt[NSEGP];
    __shared__ int lstart[NSEGP];
    __shared__ int lofs[NSEGP];
    __shared__ int gbase[NSEGP];
    __shared__ unsigned short sorted_[EPB];
    __shared__ unsigned short dstsh[EPB];   // node id < 65536 -> ushort ok
    __shared__ unsigned short srcsh[EPB];   // node id < 65536 -> ushort ok
    const int tid = threadIdx.x;
    const int e0  = blockIdx.x * EPB;

    lcnt[tid] = 0;                          // NSEGP == BLKA
    __syncthreads();
    // pass 1: coalesced src/dst read, stage in LDS, per-seg counts
    for (int i = tid; i < EPB; i += BLKA) {
        int d = dst[e0 + i];
        int s = src[e0 + i];
        dstsh[i] = (unsigned short)d;
        srcsh[i] = (unsigned short)s;
        atomicAdd(&lcnt[d >> 7], 1);
    }
    __syncthreads();
    // wave0: exclusive prefix over 512 counters; other waves: reserve
    // global ranges (one atomic per non-empty (block,seg))
    if (tid < 64) {
        int b8 = tid * 8, v[8], s0 = 0;
        #pragma unroll
        for (int k = 0; k < 8; ++k) { v[k] = lcnt[b8 + k]; s0 += v[k]; }
        int run = s0;
        #pragma unroll
        for (int off = 1; off < 64; off <<= 1) {
            int y = __shfl_up(run, off);
            if (tid >= off) run += y;
        }
        int acc = run - s0;
        #pragma unroll
        for (int k = 0; k < 8; ++k) {
            lstart[b8 + k] = acc; lofs[b8 + k] = acc; acc += v[k];
        }
    } else {
        for (int s = tid - 64; s < NSEG; s += BLKA - 64) {
            int c = lcnt[s];
            gbase[s] = c ? atomicAdd(&segcnt[s], c) : 0;
        }
    }
    __syncthreads();
    // pass 2: scatter edge indices into seg-sorted LDS order (LDS-only reads)
    for (int i = tid; i < EPB; i += BLKA) {
        int r = atomicAdd(&lofs[dstsh[i] >> 7], 1);
        sorted_[r] = (unsigned short)i;
    }
    __syncthreads();
    // pass 3: emit in sorted order; only scattered global read is the sh row
    for (int j = tid; j < EPB; j += BLKA) {
        int i = sorted_[j];
        int d = dstsh[i];
        int s = d >> 7;
        int pos = gbase[s] + (j - lstart[s]);
        if (pos < CAPE) {
            size_t gi = (size_t)s * CAPE + pos;
            meta[gi] = (int)srcsh[i] | ((d & 127) << 16);
            const float4* shv = (const float4*)(sh + (size_t)(e0 + i) * D_SH);
            float4 f0 = shv[0], f1 = shv[1], f2 = shv[2], f3 = shv[3];
            union { __half2 h[8]; int4 v[2]; } u;
            u.h[0] = __floats2half2_rn(f0.x, f0.y);
            u.h[1] = __floats2half2_rn(f0.z, f0.w);
            u.h[2] = __floats2half2_rn(f1.x, f1.y);
            u.h[3] = __floats2half2_rn(f1.z, f1.w);
            u.h[4] = __floats2half2_rn(f2.x, f2.y);
            u.h[5] = __floats2half2_rn(f2.z, f2.w);
            u.h[6] = __floats2half2_rn(f3.x, f3.y);
            u.h[7] = __floats2half2_rn(f3.z, f3.w);
            int4* dp = (int4*)(sh16 + gi * 16);
            dp[0] = u.v[0]; dp[1] = u.v[1];
        }
    }
}

__global__ __launch_bounds__(BLKA) void bin_xc(
        const float* __restrict__ x, const int* __restrict__ ki,
        __half* __restrict__ xc_h) {
    // one wave -> 4 nodes; 8 waves/block -> 32 nodes/block
    const int tid  = threadIdx.x;
    const int lane = tid & 63;
    const int w    = tid >> 6;
    const int nb   = blockIdx.x * 32 + w * 4;
    const int kil  = ki[lane];
    #pragma unroll
    for (int k = 0; k < 4; ++k) {
        int n = nb + k;
        if (n < N_NODES)
            xc_h[(size_t)n * N_PATHS + lane] =
                __float2half_rn(x[(size_t)n * D_IN + kil]);
    }
}

__global__ __launch_bounds__(BLK2) void node_kernel(
        const int* __restrict__ segcnt, const int* __restrict__ meta,
        const __half* __restrict__ sh16, const __half* __restrict__ xc_h,
        const float* __restrict__ coeff, const int* __restrict__ kj,
        const int* __restrict__ ko, float* __restrict__ out) {
    __shared__ int metash[CAPE];                        // 10 KB
    __shared__ int cnt_l[QN];
    __shared__ int nstart[QN + 1];
    __shared__ int ncur[QN];
    __shared__ unsigned short csr_src[QCAP];
    __shared__ unsigned short csr_idx[QCAP];
    __shared__ float srow[BLK2 / 64][D_OUT];            // 4 KB
    const int tid  = threadIdx.x;
    const int lane = tid & 63;
    const int w    = tid >> 6;

    const int   kj_p = kj[lane];
    const int   ko_p = ko[lane];
    const float c_p  = coeff[lane];

    // two static units per block: bid and bid+NNB (782*2 = 1564 units).
    // All 782 blocks co-resident -> no ragged second generation.
    #pragma unroll 1
    for (int uu = 0; uu < 2; ++uu) {
        const int unit = blockIdx.x + uu * NNB;
        const int seg  = unit >> 2;
        const int q    = unit & 3;
        const int nb_l = q * QN;             // local node base within segment
        const int n_e  = min(segcnt[seg], CAPE);
        const size_t mb = (size_t)seg * CAPE;
        const __half* shb = sh16 + mb * 16;

        if (tid < QN) cnt_l[tid] = 0;
        __syncthreads();   // fences prev unit's csr/gather + cnt_l reset
        // pass 1: stage meta in LDS + count this quarter's nodes (ONE
        // global pass; scatter pass below reads LDS)
        for (int i = tid; i < n_e; i += BLK2) {
            int m = meta[mb + i];
            metash[i] = m;
            unsigned int u = (unsigned)(((m >> 16) & 127) - nb_l);
            if (u < QN) atomicAdd(&cnt_l[u], 1);
        }
        __syncthreads();
        if (tid < QN) {                      // prefix over 32 counters (wave 0)
            int v = cnt_l[tid];
            int run = v;
            #pragma unroll
            for (int off = 1; off < QN; off <<= 1) {
                int y = __shfl_up(run, off);
                if (tid >= off) run += y;
            }
            nstart[tid] = run - v;
            ncur[tid]   = run - v;
            if (tid == QN - 1) nstart[QN] = run;
        }
        __syncthreads();
        // pass 2: CSR scatter FROM LDS (no second global read)
        for (int i = tid; i < n_e; i += BLK2) {
            int m = metash[i];
            unsigned int u = (unsigned)(((m >> 16) & 127) - nb_l);
            if (u < QN) {
                int r = atomicAdd(&ncur[u], 1);
                if (r < QCAP) {
                    csr_src[r] = (unsigned short)(m & 0xFFFF);
                    csr_idx[r] = (unsigned short)i;
                }
            }
        }
        __syncthreads();

        // gather: wave w owns local nodes w*4 .. w*4+3, register accumulation
        #pragma unroll 1
        for (int k = 0; k < QN / (BLK2 / 64); ++k) {
            const int c    = w * (QN / (BLK2 / 64)) + k;
            const int node = seg * SEGN + nb_l + c;
            const int st   = min(nstart[c], QCAP);
            const int en   = min(nstart[c + 1], QCAP);
            float acc = 0.0f;
            int j = st;
            for (; j + 8 <= en; j += 8) {
                float xv[8], sv[8];
                #pragma unroll
                for (int u8 = 0; u8 < 8; ++u8) {
                    int s = csr_src[j + u8];     // LDS broadcast (uniform addr)
                    int i = csr_idx[j + u8];
                    xv[u8] = __half2float(xc_h[(size_t)s * N_PATHS + lane]);
                    sv[u8] = __half2float(shb[(size_t)i * 16 + kj_p]);
                }
                #pragma unroll
                for (int u8 = 0; u8 < 8; ++u8) acc += xv[u8] * sv[u8];
            }
            if (j < en) {                        // masked final group (1..7)
                float xv[8], sv[8];
                #pragma unroll
                for (int u8 = 0; u8 < 8; ++u8) {
                    int jj = j + u8;
                    int jc = jj < en ? jj : st;  // st valid (en > st here)
                    int s = csr_src[jc];
                    int i = csr_idx[jc];
                    xv[u8] = __half2float(xc_h[(size_t)s * N_PATHS + lane]);
                    sv[u8] = __half2float(shb[(size_t)i * 16 + kj_p]);
                }
                #pragma unroll
                for (int u8 = 0; u8 < 8; ++u8)
                    if (j + u8 < en) acc += xv[u8] * sv[u8];
            }
            acc *= c_p;
            if (node < N_NODES) {
                // combine equal-ko lanes through the wave's PRIVATE LDS row.
                // per-wave DS ops are in-order -> no barriers (proven R8-R17)
                srow[w][lane]      = 0.0f;
                srow[w][lane + 64] = 0.0f;
                atomicAdd(&srow[w][ko_p], acc);
                float r0 = srow[w][lane];
                float r1 = srow[w][lane + 64];
                float* orow = out + (size_t)node * D_OUT;
                orow[lane]      = r0;
                orow[lane + 64] = r1;
            }
        }
    }
}

extern "C" void kernel_launch(void* const* d_in, const int* in_sizes, int n_in,
                              void* d_out, int out_size, void* d_ws, size_t ws_size,
                              hipStream_t stream) {
    const float* x     = (const float*)d_in[0];
    const float* sh    = (const float*)d_in[1];
    const float* coeff = (const float*)d_in[2];
    const int*   src   = (const int*)d_in[3];
    const int*   dst   = (const int*)d_in[4];
    const int*   ki    = (const int*)d_in[5];
    const int*   kj    = (const int*)d_in[6];
    const int*   ko    = (const int*)d_in[7];
    float* out = (float*)d_out;

    char* p = (char*)d_ws;
    int*    segcnt = (int*)p;
    int*    meta   = (int*)(p + OFF_META);
    __half* sh16   = (__half*)(p + OFF_SH16);
    __half* xc_h   = (__half*)(p + OFF_XCH);
    (void)ws_size;   // need 42.4 MB; harness provides >= 57.8 MB

    hipMemsetAsync(p, 0, 2048, stream);   // segcnt
    bin_xc<<<XCB, BLKA, 0, stream>>>(x, ki, xc_h);
    bin_scatter<<<BINB, BLKA, 0, stream>>>(
        sh, src, dst, segcnt, meta, sh16);
    node_kernel<<<NNB, BLK2, 0, stream>>>(
        segcnt, meta, sh16, xc_h, coeff, kj, ko, out);
}